// Round 10
// baseline (322.937 us; speedup 1.0000x reference)
//
#include <hip/hip_runtime.h>

typedef unsigned short u16;
typedef unsigned int u32;
typedef __attribute__((ext_vector_type(4))) float f32x4;
typedef __attribute__((ext_vector_type(8))) short s16x8;

__device__ __forceinline__ u16 f2bf(float f) {
  union { float f; u32 u; } v; v.f = f;
  u32 u = v.u;
  return (u16)((u + 0x7fffu + ((u >> 16) & 1u)) >> 16);
}
__device__ __forceinline__ float bf2f(u16 b) {
  union { u32 u; float f; } v; v.u = ((u32)b) << 16;
  return v.f;
}
// fast sigmoid: v_rcp (1 instr, ~1ulp) instead of IEEE divide sequence.
__device__ __forceinline__ float sigmoidf(float x) {
  return __builtin_amdgcn_rcpf(1.0f + __expf(-x));
}

__device__ __forceinline__ void async16(const void* g, void* l) {
  __builtin_amdgcn_global_load_lds(
      (const __attribute__((address_space(1))) u32*)g,
      (__attribute__((address_space(3))) u32*)l, 16, 0, 0);
}

// pack 2 f32 -> u32 of 2 bf16 (RNE). Used for LDS h-writes ONLY.
// DO NOT use for the theta global store: every failed round (R4/R6/R8)
// contained pk-theta; every passing round used f2bf there. Un-diagnosed.
__device__ __forceinline__ u32 pk_bf16(float lo, float hi) {
  u32 r;
  asm("v_cvt_pk_bf16_f32 %0, %1, %2" : "=v"(r) : "v"(lo), "v"(hi));
  return r;
}

// ---------------------------------------------------------------------------
// merged prep: one launch for A-cast/copy + 5 conv-weight preps + fwT.
// ---------------------------------------------------------------------------
__device__ __forceinline__ void prep_w_body(
    const float* __restrict__ tw, u16* __restrict__ WcT,
    int CIN, int WK, int idx)
{
  if (idx >= 128 * WK) return;
  const int c = idx / WK;
  const int k = idx - c * WK;
  const int KR = CIN * 3;
  float v = 0.0f;
  if (k < KR) {
    const int k3 = k / CIN, cin = k - k3 * CIN;
    if (c < 64)
      v = tw[(k3 * CIN + cin) * 64 + c] + tw[(3 * CIN + k3 * CIN + cin) * 64 + c];
    else
      v = tw[(6 * CIN + k3 * CIN + cin) * 64 + (c - 64)];
  }
  WcT[idx] = f2bf(v);
}

__global__ __launch_bounds__(256) void prep_all(
    const float* __restrict__ A, u16* __restrict__ Abf, float* __restrict__ outA,
    const float* __restrict__ tb1w, u16* __restrict__ W1,
    const float* __restrict__ tb2w, u16* __restrict__ W2,
    const float* __restrict__ tb3w, u16* __restrict__ W3,
    const float* __restrict__ tb4w, u16* __restrict__ W4,
    const float* __restrict__ tb5w, u16* __restrict__ W5,
    const float* __restrict__ fw, u16* __restrict__ FWT)
{
  const int bx = blockIdx.x;
  const int tid = threadIdx.x;
  if (bx < 4096) {
    const long i = ((long)bx * 256 + tid) * 4;
    float4 v = *(const float4*)(A + i);
    *(float4*)(outA + i) = v;
    ushort4 p;
    p.x = f2bf(v.x); p.y = f2bf(v.y); p.z = f2bf(v.z); p.w = f2bf(v.w);
    *(ushort4*)(Abf + i) = p;
  } else if (bx < 4100) {
    prep_w_body(tb1w, W1, 2, 8, (bx - 4096) * 256 + tid);
  } else if (bx < 4132) {
    prep_w_body(tb2w, W2, 16, 64, (bx - 4100) * 256 + tid);
  } else if (bx < 4228) {
    prep_w_body(tb3w, W3, 64, 192, (bx - 4132) * 256 + tid);
  } else if (bx < 4260) {
    prep_w_body(tb4w, W4, 16, 64, (bx - 4228) * 256 + tid);
  } else if (bx < 4356) {
    prep_w_body(tb5w, W5, 64, 192, (bx - 4260) * 256 + tid);
  } else {
    const int idx = (bx - 4356) * 256 + tid;
    if (idx < 16 * 896) {
      const int p = idx / 896, k = idx - p * 896;
      FWT[idx] = f2bf(p < 12 ? fw[k * 12 + p] : 0.0f);
    }
  }
}

// ---------------------------------------------------------------------------
// TB1 + theta1, full MFMA. x [16][2048][24][2] fp32. W1 [128][8] bf16 prepped.
// Output U1[(b*22+t)*16+p][n] bf16, packed b64 stores.
// ---------------------------------------------------------------------------
__global__ __launch_bounds__(256) void tb1_kernel(
    const float* __restrict__ x, const u16* __restrict__ W1,
    const float* __restrict__ bias, const float* __restrict__ th1,
    u16* __restrict__ U1)
{
  __shared__ float Bts[64], Bgs[64];
  __shared__ u16 t2buf[4][16 * 64];
  const int tid = threadIdx.x;
  if (tid < 64) { Bts[tid] = bias[tid] + bias[64 + tid]; Bgs[tid] = bias[128 + tid]; }
  const int lane = tid & 63, w = tid >> 6;
  const int lm = lane & 15, q = lane >> 4;
  const int b = blockIdx.y, t = blockIdx.z;
  const int n0 = blockIdx.x * 256 + w * 64;

  s16x8 wfrag[8];
#pragma unroll
  for (int mt = 0; mt < 8; mt++) {
    wfrag[mt] = (s16x8){0, 0, 0, 0, 0, 0, 0, 0};
    if (q == 0) wfrag[mt] = *(const s16x8*)(W1 + (mt * 16 + lm) * 8);
  }
  s16x8 tfrag[2];
#pragma unroll
  for (int kk = 0; kk < 2; kk++)
#pragma unroll
    for (int j = 0; j < 8; j++)
      tfrag[kk][j] = (short)f2bf(th1[(kk * 32 + q * 8 + j) * 16 + lm]);

  float xv[4][6];
  if (q == 0) {
#pragma unroll
    for (int nt = 0; nt < 4; nt++) {
      const float* xp = x + ((long)(b * 2048 + n0 + nt * 16 + lm) * 24 + t) * 2;
#pragma unroll
      for (int j = 0; j < 6; j++) xv[nt][j] = xp[j];
    }
  }
  __syncthreads();
  float bt4[4][4], bg4[4][4];
#pragma unroll
  for (int mt = 0; mt < 4; mt++)
#pragma unroll
    for (int r = 0; r < 4; r++) {
      bt4[mt][r] = Bts[mt * 16 + q * 4 + r];
      bg4[mt][r] = Bgs[mt * 16 + q * 4 + r];
    }

  u16* myt2 = t2buf[w];
  const long orowbase = (long)((b * 22 + t) * 16) << 11;

#pragma unroll
  for (int nt = 0; nt < 4; nt++) {
    s16x8 pfrag = (s16x8){0, 0, 0, 0, 0, 0, 0, 0};
    if (q == 0) {
#pragma unroll
      for (int j = 0; j < 6; j++) pfrag[j] = (short)f2bf(xv[nt][j]);
    }
    f32x4 acc1[8];
#pragma unroll
    for (int mt = 0; mt < 8; mt++) acc1[mt] = f32x4{0.f, 0.f, 0.f, 0.f};
#pragma unroll
    for (int mt = 0; mt < 8; mt++)
      acc1[mt] = __builtin_amdgcn_mfma_f32_16x16x32_bf16(wfrag[mt], pfrag, acc1[mt], 0, 0, 0);

#pragma unroll
    for (int mt = 0; mt < 4; mt++) {
      u32 pk[2];
      u16 pv[4];
#pragma unroll
      for (int r = 0; r < 4; r++) {
        const float temp = acc1[mt][r] + bt4[mt][r];
        const float ga = acc1[mt + 4][r] + bg4[mt][r];
        pv[r] = f2bf(fmaxf(temp * sigmoidf(ga), 0.0f));
      }
      pk[0] = (u32)pv[0] | ((u32)pv[1] << 16);
      pk[1] = (u32)pv[2] | ((u32)pv[3] << 16);
      const int g = (mt * 4 + q) >> 1, half = q & 1;
      *(uint2*)(myt2 + lm * 64 + (g ^ (lm & 7)) * 8 + half * 4) = make_uint2(pk[0], pk[1]);
    }

    f32x4 acc2 = f32x4{0.f, 0.f, 0.f, 0.f};
#pragma unroll
    for (int kk = 0; kk < 2; kk++) {
      s16x8 af = *(const s16x8*)(myt2 + lm * 64 + ((kk * 4 + q) ^ (lm & 7)) * 8);
      acc2 = __builtin_amdgcn_mfma_f32_16x16x32_bf16(af, tfrag[kk], acc2, 0, 0, 0);
    }
    u16 ov[4];
#pragma unroll
    for (int r = 0; r < 4; r++) ov[r] = f2bf(acc2[r]);
    *(uint2*)(U1 + orowbase + ((long)lm << 11) + n0 + nt * 16 + q * 4) =
        make_uint2((u32)ov[0] | ((u32)ov[1] << 16), (u32)ov[2] | ((u32)ov[3] << 16));
  }
}

// ---------------------------------------------------------------------------
// Spatial GEMM (NT): C[i,col] = sum_j A[i,j] * X[col, j]  (+ optional relu)
// R1 structure + bijective XCD swizzle (verified R9: passed, sp_gemm off the
// top-5). Do not re-pipeline (R2 regression).
// ---------------------------------------------------------------------------
template <int RELU>
__global__ __launch_bounds__(256, 3) void sp_gemm(
    const u16* __restrict__ A, const u16* __restrict__ X,
    u16* __restrict__ C, int Ncols, int nwg)
{
  __shared__ u16 ldsA[128 * 64];
  __shared__ u16 ldsB[128 * 64];
  const int lane = threadIdx.x & 63;
  const int w = threadIdx.x >> 6;

  const int h = blockIdx.x;
  const int bx = (h & 7) * (nwg >> 3) + (h >> 3);   // bijective for nwg%8==0

  const int ct = bx >> 4;
  const int rt = bx & 15;
  const int i0 = rt * 128;
  const int c0 = ct * 128;

  const int wm = w & 1, wn = w >> 1;
  const int lm = lane & 15, q = lane >> 4;

  f32x4 acc[4][4];
#pragma unroll
  for (int a = 0; a < 4; a++)
#pragma unroll
    for (int b2 = 0; b2 < 4; b2++) acc[a][b2] = f32x4{0.f, 0.f, 0.f, 0.f};

  const int srow = lane >> 3;
  const int sg = (lane & 7) ^ srow;
  const u16* gA = A + ((long)(i0 + w * 32 + srow) << 11) + sg * 8;
  const u16* gB = X + ((long)(c0 + w * 32 + srow) << 11) + sg * 8;
  u16* lA = ldsA + w * 2048;
  u16* lB = ldsB + w * 2048;

  for (int k0 = 0; k0 < 2048; k0 += 64) {
    __syncthreads();
#pragma unroll
    for (int j = 0; j < 4; j++) {
      async16(gA + j * 16384 + k0, lA + j * 512);
      async16(gB + j * 16384 + k0, lB + j * 512);
    }
    __syncthreads();
#pragma unroll
    for (int kk = 0; kk < 2; kk++) {
      const int ph = (kk * 4 + q) ^ (lm & 7);
      s16x8 af[4], bfr[4];
#pragma unroll
      for (int mt = 0; mt < 4; mt++)
        af[mt] = *(const s16x8*)(ldsA + (wm * 64 + mt * 16 + lm) * 64 + ph * 8);
#pragma unroll
      for (int nt = 0; nt < 4; nt++)
        bfr[nt] = *(const s16x8*)(ldsB + (wn * 64 + nt * 16 + lm) * 64 + ph * 8);
#pragma unroll
      for (int mt = 0; mt < 4; mt++)
#pragma unroll
        for (int nt = 0; nt < 4; nt++)
          acc[mt][nt] = __builtin_amdgcn_mfma_f32_16x16x32_bf16(af[mt], bfr[nt], acc[mt][nt], 0, 0, 0);
    }
  }

#pragma unroll
  for (int mt = 0; mt < 4; mt++) {
#pragma unroll
    for (int r = 0; r < 4; r++) {
      const long i = i0 + wm * 64 + mt * 16 + q * 4 + r;
      u16* crow = C + i * Ncols + c0 + wn * 64 + lm;
#pragma unroll
      for (int nt = 0; nt < 4; nt++) {
        float v = acc[mt][nt][r];
        if (RELU) v = fmaxf(v, 0.0f);
        crow[nt * 16] = f2bf(v);
      }
    }
  }
}

// ---------------------------------------------------------------------------
// Fused timeblock pair v7 = R9-verified kernel + ONE change: MODE1 t-split
// x2 (grid 1024; block h owns outputs [9h, 9h+9)). Everything else — gates,
// ladder CODE (j<3 -> vmcnt(1) else vmcnt(2)), h-swizzle, rcp sigmoid,
// f2bf theta store — is R9-verbatim. Ladder re-verified by queue simulation
// for both halves; the one past-end seg (h=1, j=6 -> seg 22) is a zero-tap:
// address clamps to TIN-1, slot keeps its intended index, W1c taps k>=48
// are zero so garbage-finite data is harmless.
// This round is also the controlled test of the pk-theta-poison hypothesis:
// all failures (R4/R6/R8) contained pk-theta; t-split was never tested
// without it. Pass -> pk-theta convicted; fail -> t-split convicted, revert.
// PARKED (do not re-roll): pk_bf16 theta store; R8 bias-fold into MFMA C.
// ---------------------------------------------------------------------------
template <int TIN, int MODE>
__global__ __launch_bounds__(256, 2) void tbf_fused(
    const u16* __restrict__ in, const u16* __restrict__ W1c,
    const float* __restrict__ b1, const u16* __restrict__ W2c,
    const float* __restrict__ b2, const float* __restrict__ th,
    const u16* __restrict__ fwT, const float* __restrict__ fb,
    u16* __restrict__ outU, float* __restrict__ outF)
{
  constexpr int T2OUT = TIN - 4;            // TB-second outputs (total)
  constexpr int NC = TIN * 256;             // input row stride (u16)
  constexpr int NSP = (MODE == 1) ? 2 : 1;
  constexpr int T2H = T2OUT / NSP;          // outputs per block: 9 / 14
  constexpr int NI  = T2H + 2;              // iters: 11 / 16
  constexpr int JISS = (MODE == 1) ? 6 : 10;  // last j that issues a pair

  __shared__ __align__(16) u16 ring[8 * 1024];       // 16384 B
  __shared__ __align__(16) u16 h2r[3 * 64 * 64];     // 24576 B
  __shared__ __align__(16) u16 h3b[64 * 64];         //  8192 B
  __shared__ __align__(16) u16 sfw[(MODE == 0) ? 12 * 904 : 8];  // 21696 B (MODE0)

  const int tid = threadIdx.x;
  const int lane = tid & 63;
  const int w = tid >> 6;
  const int lm = lane & 15, q = lane >> 4;
  const int bx = blockIdx.x;
  const int n0 = (bx & 31) << 6;
  const int b = (bx >> 5) & 15;
  const int t0 = (MODE == 1) ? ((bx >> 9) * T2H) : 0;

  // ---- weights -> regs (A-operand: row lm = out-channel w*16+lm) ---------
  s16x8 wfA[2][2];
  {
    const u16* wp = W1c + (w * 16 + lm) * 64 + q * 8;
#pragma unroll
    for (int kk = 0; kk < 2; kk++) {
      wfA[0][kk] = *(const s16x8*)(wp + kk * 32);
      wfA[1][kk] = *(const s16x8*)(wp + 64 * 64 + kk * 32);
    }
  }
  s16x8 wfB[2][6];
  {
    const u16* wp = W2c + (w * 16 + lm) * 192 + q * 8;
#pragma unroll
    for (int kk = 0; kk < 6; kk++) {
      wfB[0][kk] = *(const s16x8*)(wp + kk * 32);
      wfB[1][kk] = *(const s16x8*)(wp + 64 * 192 + kk * 32);
    }
  }
  // per-lane channel block for swapped-D epilogues: ch = cw + r
  const int cw = w * 16 + q * 4;
  float bsA4[4], bgA4[4], bsB4[4], bgB4[4];
#pragma unroll
  for (int r = 0; r < 4; r++) {
    bsA4[r] = b1[cw + r] + b1[64 + cw + r];
    bgA4[r] = b1[128 + cw + r];
    bsB4[r] = b2[cw + r] + b2[64 + cw + r];
    bgB4[r] = b2[128 + cw + r];
  }

  s16x8 tfrag[2];
  const int srow12 = (lm < 12) ? lm : (lm - 12);
  if constexpr (MODE == 1) {
#pragma unroll
    for (int kk = 0; kk < 2; kk++)
#pragma unroll
      for (int j = 0; j < 8; j++)
        tfrag[kk][j] = (short)f2bf(th[(kk * 32 + q * 8 + j) * 16 + lm]);
  } else {
    // FC weights: 12 real p-rows, stride 904 (16B mult, bank-spread).
#pragma unroll
    for (int i = 0; i < 6; i++) {
      const int g = i * 256 + tid;              // granules of 8 u16
      if (g < 12 * 112) {
        const int p = g / 112, k8 = g - p * 112;
        *(s16x8*)(sfw + p * 904 + k8 * 8) = *(const s16x8*)(fwT + g * 8);
      }
    }
  }
  // materialize prologue VGPR loads, then drain VM queue so the counted
  // vmcnt ladder below sees only segment loads (+ MODE1 theta stores).
  asm volatile("" : "+v"(bsA4[0]), "+v"(bsA4[1]), "+v"(bsA4[2]), "+v"(bsA4[3]),
                    "+v"(bgA4[0]), "+v"(bgA4[1]), "+v"(bgA4[2]), "+v"(bgA4[3]),
                    "+v"(bsB4[0]), "+v"(bsB4[1]), "+v"(bsB4[2]), "+v"(bsB4[3]),
                    "+v"(bgB4[0]), "+v"(bgB4[1]), "+v"(bgB4[2]), "+v"(bgB4[3]));
  asm volatile("s_waitcnt vmcnt(0)" ::: "memory");

  // ---- segment staging: pairs of 2 t-steps, all 256 threads, 1 load each --
  const int k7 = tid & 127;                   // position within a seg (x16B)
  const int segsel = tid >> 7;                // 0/1: which seg of the pair
  const u16* rowp = in + (long)(n0 + (k7 >> 1)) * NC + (long)(b * TIN) * 16 + (k7 & 1) * 8;

  auto issue_pair = [&](int tp) {
    const int seg = tp + segsel;
    const int sega = (seg < TIN) ? seg : (TIN - 1);   // past-end seg = zero-tap:
    async16(rowp + sega * 16,                          // clamp addr, keep slot
            ring + ((seg & 7) << 10) + k7 * 8);
  };

  issue_pair(t0); issue_pair(t0 + 2); issue_pair(t0 + 4);  // segs t0..t0+5

  u16* h2w = h2r;                 // h(t)   write slot
  u16* h2m = h2r + 64 * 64;       // h(t-1)
  u16* h2o = h2r + 2 * 64 * 64;   // h(t-2)
  f32x4 accfc = f32x4{0.f, 0.f, 0.f, 0.f};

  const int gw8 = 2 * w + (q >> 1);   // granule of cw within a 64-u16 h row
  const int wofs = (q & 1) << 2;      // u16 offset within granule

#pragma unroll 1
  for (int j = 0; j < NI; ++j) {
    const int t = t0 + j;
    // gate: required pair retired. MODE1 queue per iter = {L, S}; MODE0 = {L}.
    if constexpr (MODE == 1) {
      if (j < 3) asm volatile("s_waitcnt vmcnt(1) lgkmcnt(0)" ::: "memory");
      else       asm volatile("s_waitcnt vmcnt(2) lgkmcnt(0)" ::: "memory");
    } else {
      if (j < 13) asm volatile("s_waitcnt vmcnt(1) lgkmcnt(0)" ::: "memory");
      else        asm volatile("s_waitcnt vmcnt(0) lgkmcnt(0)" ::: "memory");
    }
    __builtin_amdgcn_s_barrier();

    if (((j & 1) == 0) && j <= JISS) issue_pair(t + 6);

    // ---- TB-first: K=64 window over ring segs t..t+3 (swapped operands) --
    {
      f32x4 aA[4][2];
#pragma unroll
      for (int m = 0; m < 4; m++) {
        aA[m][0] = f32x4{0.f, 0.f, 0.f, 0.f};
        aA[m][1] = f32x4{0.f, 0.f, 0.f, 0.f};
      }
#pragma unroll
      for (int kk = 0; kk < 2; kk++) {
        const int slotb = ((t + 2 * kk + (q >> 1)) & 7) << 10;
        const int off = slotb + (q & 1) * 8;
#pragma unroll
        for (int nt = 0; nt < 4; nt++) {
          s16x8 pf = *(const s16x8*)(ring + off + (nt * 16 + lm) * 16);
          aA[nt][0] = __builtin_amdgcn_mfma_f32_16x16x32_bf16(wfA[0][kk], pf, aA[nt][0], 0, 0, 0);
          aA[nt][1] = __builtin_amdgcn_mfma_f32_16x16x32_bf16(wfA[1][kk], pf, aA[nt][1], 0, 0, 0);
        }
      }
      // gate epilogue -> h2w (swizzled b64: node nt*16+lm, ch cw..cw+3)
#pragma unroll
      for (int nt = 0; nt < 4; nt++) {
        float hv[4];
#pragma unroll
        for (int r = 0; r < 4; r++) {
          const float temp = aA[nt][0][r] + bsA4[r];
          const float ga = aA[nt][1][r] + bgA4[r];
          hv[r] = fmaxf(temp * sigmoidf(ga), 0.0f);
        }
        *(uint2*)(h2w + ((nt * 16 + lm) << 6) + ((gw8 ^ (lm & 7)) << 3) + wofs) =
            make_uint2(pk_bf16(hv[0], hv[1]), pk_bf16(hv[2], hv[3]));
      }
    }
    asm volatile("s_waitcnt lgkmcnt(0)" ::: "memory");
    __builtin_amdgcn_s_barrier();

    if (j >= 2) {
      // ---- TB-second: K=192 over h(t-2), h(t-1), h(t) (swizzled reads) ---
      f32x4 aB[4][2];
#pragma unroll
      for (int m = 0; m < 4; m++) {
        aB[m][0] = f32x4{0.f, 0.f, 0.f, 0.f};
        aB[m][1] = f32x4{0.f, 0.f, 0.f, 0.f};
      }
#pragma unroll
      for (int kk3 = 0; kk3 < 6; kk3++) {
        const u16* hp = (kk3 < 2) ? h2o : ((kk3 < 4) ? h2m : h2w);
        const int gr = (kk3 & 1) * 4 + q;
#pragma unroll
        for (int nt = 0; nt < 4; nt++) {
          s16x8 pf = *(const s16x8*)(hp + ((nt * 16 + lm) << 6) + ((gr ^ (lm & 7)) << 3));
          aB[nt][0] = __builtin_amdgcn_mfma_f32_16x16x32_bf16(wfB[0][kk3], pf, aB[nt][0], 0, 0, 0);
          aB[nt][1] = __builtin_amdgcn_mfma_f32_16x16x32_bf16(wfB[1][kk3], pf, aB[nt][1], 0, 0, 0);
        }
      }
      // gate epilogue -> h3b (swizzled b64)
#pragma unroll
      for (int nt = 0; nt < 4; nt++) {
        float hv[4];
#pragma unroll
        for (int r = 0; r < 4; r++) {
          const float temp = aB[nt][0][r] + bsB4[r];
          const float ga = aB[nt][1][r] + bgB4[r];
          hv[r] = fmaxf(temp * sigmoidf(ga), 0.0f);
        }
        *(uint2*)(h3b + ((nt * 16 + lm) << 6) + ((gw8 ^ (lm & 7)) << 3) + wofs) =
            make_uint2(pk_bf16(hv[0], hv[1]), pk_bf16(hv[2], hv[3]));
      }
      asm volatile("s_waitcnt lgkmcnt(0)" ::: "memory");
      __builtin_amdgcn_s_barrier();

      const int o2 = t - 2;
      if constexpr (MODE == 1) {
        f32x4 a4 = f32x4{0.f, 0.f, 0.f, 0.f};
#pragma unroll
        for (int kk = 0; kk < 2; kk++) {
          s16x8 af = *(const s16x8*)(h3b + ((w * 16 + lm) << 6) + (((kk * 4 + q) ^ (lm & 7)) << 3));
          a4 = __builtin_amdgcn_mfma_f32_16x16x32_bf16(af, tfrag[kk], a4, 0, 0, 0);
        }
        u16 ov[4];
#pragma unroll
        for (int r = 0; r < 4; r++) ov[r] = f2bf(a4[r]);
        const long orowbase = (long)((b * T2OUT + o2) * 16) << 11;
        *(uint2*)(outU + orowbase + ((long)lm << 11) + n0 + w * 16 + q * 4) =
            make_uint2((u32)ov[0] | ((u32)ov[1] << 16), (u32)ov[2] | ((u32)ov[3] << 16));
      } else {
#pragma unroll
        for (int kk = 0; kk < 2; kk++) {
          s16x8 af = *(const s16x8*)(h3b + ((w * 16 + lm) << 6) + (((kk * 4 + q) ^ (lm & 7)) << 3));
          s16x8 bfr = *(const s16x8*)(sfw + srow12 * 904 + o2 * 64 + kk * 32 + q * 8);
          accfc = __builtin_amdgcn_mfma_f32_16x16x32_bf16(af, bfr, accfc, 0, 0, 0);
        }
      }
    }
    // rotate h slots: (t-2) slot becomes next write slot
    u16* tmp = h2o; h2o = h2m; h2m = h2w; h2w = tmp;
  }

  if constexpr (MODE == 0) {
    if (lm < 12) {
      const float bfc = fb[lm];
#pragma unroll
      for (int r = 0; r < 4; r++) {
        const int n = n0 + w * 16 + q * 4 + r;
        outF[((long)b * 2048 + n) * 12 + lm] = accfc[r] + bfc;
      }
    }
  }
}

// ---------------------------------------------------------------------------
extern "C" void kernel_launch(void* const* d_in, const int* in_sizes, int n_in,
                              void* d_out, int out_size, void* d_ws, size_t ws_size,
                              hipStream_t stream)
{
  const float* x    = (const float*)d_in[0];
  const float* A    = (const float*)d_in[1];
  const float* tb1w = (const float*)d_in[2];
  const float* tb1b = (const float*)d_in[3];
  const float* th1  = (const float*)d_in[4];
  const float* tb2w = (const float*)d_in[5];
  const float* tb2b = (const float*)d_in[6];
  const float* tb3w = (const float*)d_in[7];
  const float* tb3b = (const float*)d_in[8];
  const float* th2  = (const float*)d_in[9];
  const float* tb4w = (const float*)d_in[10];
  const float* tb4b = (const float*)d_in[11];
  const float* tb5w = (const float*)d_in[12];
  const float* tb5b = (const float*)d_in[13];
  const float* fw   = (const float*)d_in[14];
  const float* fb   = (const float*)d_in[15];
  float* out = (float*)d_out;

  char* ws = (char*)d_ws;
  u16* Abf  = (u16*)(ws + 0);            //  8,388,608 B
  u16* W2   = (u16*)(ws + 8388608);      //     16,384
  u16* W3   = (u16*)(ws + 8404992);      //     49,152
  u16* W4   = (u16*)(ws + 8454144);      //     16,384
  u16* W5   = (u16*)(ws + 8470528);      //     49,152
  u16* bufA = (u16*)(ws + 8519680);      // 92,274,688
  u16* bufB = (u16*)(ws + 100794368);    // 92,274,688
  u16* W1   = (u16*)(ws + 8519680 + 88000000);  // 2 KB, in bufA tail slack
  u16* FWT  = (u16*)(ws + 8519680 + 88004096);  // 28,672 B, bufA tail slack

  prep_all<<<4412, 256, 0, stream>>>(A, Abf, out + 393216,
                                     tb1w, W1, tb2w, W2, tb3w, W3,
                                     tb4w, W4, tb5w, W5, fw, FWT);

  // ---- block 1:  U1 = TB1(x)*th1; t2 = relu(A*U1); U2 = TB3(TB2(t2))*th2
  tb1_kernel<<<dim3(8, 16, 22), 256, 0, stream>>>(x, W1, tb1b, th1, bufA);
  sp_gemm<1><<<44 * 16, 256, 0, stream>>>(Abf, bufA, bufB, 5632, 44 * 16);
  tbf_fused<22, 1><<<1024, 256, 0, stream>>>(bufB, W2, tb2b, W3, tb3b, th2,
                                             nullptr, nullptr, bufA, nullptr);
  // ---- block 2:  t2 = relu(A*U2); out = FC(TB5(TB4(t2)))
  sp_gemm<1><<<36 * 16, 256, 0, stream>>>(Abf, bufA, bufB, 4608, 36 * 16);
  tbf_fused<18, 0><<<512, 256, 0, stream>>>(bufB, W4, tb4b, W5, tb5b, nullptr,
                                            FWT, fb, nullptr, out);
}

// Round 11
// 299.373 us; speedup vs baseline: 1.0787x; 1.0787x over previous
//
#include <hip/hip_runtime.h>

typedef unsigned short u16;
typedef unsigned int u32;
typedef __attribute__((ext_vector_type(4))) float f32x4;
typedef __attribute__((ext_vector_type(8))) short s16x8;

__device__ __forceinline__ u16 f2bf(float f) {
  union { float f; u32 u; } v; v.f = f;
  u32 u = v.u;
  return (u16)((u + 0x7fffu + ((u >> 16) & 1u)) >> 16);
}
__device__ __forceinline__ float bf2f(u16 b) {
  union { u32 u; float f; } v; v.u = ((u32)b) << 16;
  return v.f;
}
// fast sigmoid: v_rcp (1 instr, ~1ulp) instead of IEEE divide sequence.
__device__ __forceinline__ float sigmoidf(float x) {
  return __builtin_amdgcn_rcpf(1.0f + __expf(-x));
}

__device__ __forceinline__ void async16(const void* g, void* l) {
  __builtin_amdgcn_global_load_lds(
      (const __attribute__((address_space(1))) u32*)g,
      (__attribute__((address_space(3))) u32*)l, 16, 0, 0);
}

// pack 2 f32 -> u32 of 2 bf16 (RNE). Used for LDS h-writes ONLY.
// CONVICTED poison for the theta GLOBAL store: R4/R6/R8 (all contained
// pk-theta) NaN'd; R5/R7/R9/R10 (f2bf theta) all passed, including R10
// which isolated the t-split without pk-theta. Do not use for theta.
__device__ __forceinline__ u32 pk_bf16(float lo, float hi) {
  u32 r;
  asm("v_cvt_pk_bf16_f32 %0, %1, %2" : "=v"(r) : "v"(lo), "v"(hi));
  return r;
}

// ---------------------------------------------------------------------------
// merged prep: one launch for A-cast/copy + 5 conv-weight preps + fwT.
// ---------------------------------------------------------------------------
__device__ __forceinline__ void prep_w_body(
    const float* __restrict__ tw, u16* __restrict__ WcT,
    int CIN, int WK, int idx)
{
  if (idx >= 128 * WK) return;
  const int c = idx / WK;
  const int k = idx - c * WK;
  const int KR = CIN * 3;
  float v = 0.0f;
  if (k < KR) {
    const int k3 = k / CIN, cin = k - k3 * CIN;
    if (c < 64)
      v = tw[(k3 * CIN + cin) * 64 + c] + tw[(3 * CIN + k3 * CIN + cin) * 64 + c];
    else
      v = tw[(6 * CIN + k3 * CIN + cin) * 64 + (c - 64)];
  }
  WcT[idx] = f2bf(v);
}

__global__ __launch_bounds__(256) void prep_all(
    const float* __restrict__ A, u16* __restrict__ Abf, float* __restrict__ outA,
    const float* __restrict__ tb1w, u16* __restrict__ W1,
    const float* __restrict__ tb2w, u16* __restrict__ W2,
    const float* __restrict__ tb3w, u16* __restrict__ W3,
    const float* __restrict__ tb4w, u16* __restrict__ W4,
    const float* __restrict__ tb5w, u16* __restrict__ W5,
    const float* __restrict__ fw, u16* __restrict__ FWT)
{
  const int bx = blockIdx.x;
  const int tid = threadIdx.x;
  if (bx < 4096) {
    const long i = ((long)bx * 256 + tid) * 4;
    float4 v = *(const float4*)(A + i);
    *(float4*)(outA + i) = v;
    ushort4 p;
    p.x = f2bf(v.x); p.y = f2bf(v.y); p.z = f2bf(v.z); p.w = f2bf(v.w);
    *(ushort4*)(Abf + i) = p;
  } else if (bx < 4100) {
    prep_w_body(tb1w, W1, 2, 8, (bx - 4096) * 256 + tid);
  } else if (bx < 4132) {
    prep_w_body(tb2w, W2, 16, 64, (bx - 4100) * 256 + tid);
  } else if (bx < 4228) {
    prep_w_body(tb3w, W3, 64, 192, (bx - 4132) * 256 + tid);
  } else if (bx < 4260) {
    prep_w_body(tb4w, W4, 16, 64, (bx - 4228) * 256 + tid);
  } else if (bx < 4356) {
    prep_w_body(tb5w, W5, 64, 192, (bx - 4260) * 256 + tid);
  } else {
    const int idx = (bx - 4356) * 256 + tid;
    if (idx < 16 * 896) {
      const int p = idx / 896, k = idx - p * 896;
      FWT[idx] = f2bf(p < 12 ? fw[k * 12 + p] : 0.0f);
    }
  }
}

// ---------------------------------------------------------------------------
// TB1 + theta1, full MFMA. x [16][2048][24][2] fp32. W1 [128][8] bf16 prepped.
// Output U1[(b*22+t)*16+p][n] bf16, packed b64 stores.
// ---------------------------------------------------------------------------
__global__ __launch_bounds__(256) void tb1_kernel(
    const float* __restrict__ x, const u16* __restrict__ W1,
    const float* __restrict__ bias, const float* __restrict__ th1,
    u16* __restrict__ U1)
{
  __shared__ float Bts[64], Bgs[64];
  __shared__ u16 t2buf[4][16 * 64];
  const int tid = threadIdx.x;
  if (tid < 64) { Bts[tid] = bias[tid] + bias[64 + tid]; Bgs[tid] = bias[128 + tid]; }
  const int lane = tid & 63, w = tid >> 6;
  const int lm = lane & 15, q = lane >> 4;
  const int b = blockIdx.y, t = blockIdx.z;
  const int n0 = blockIdx.x * 256 + w * 64;

  s16x8 wfrag[8];
#pragma unroll
  for (int mt = 0; mt < 8; mt++) {
    wfrag[mt] = (s16x8){0, 0, 0, 0, 0, 0, 0, 0};
    if (q == 0) wfrag[mt] = *(const s16x8*)(W1 + (mt * 16 + lm) * 8);
  }
  s16x8 tfrag[2];
#pragma unroll
  for (int kk = 0; kk < 2; kk++)
#pragma unroll
    for (int j = 0; j < 8; j++)
      tfrag[kk][j] = (short)f2bf(th1[(kk * 32 + q * 8 + j) * 16 + lm]);

  float xv[4][6];
  if (q == 0) {
#pragma unroll
    for (int nt = 0; nt < 4; nt++) {
      const float* xp = x + ((long)(b * 2048 + n0 + nt * 16 + lm) * 24 + t) * 2;
#pragma unroll
      for (int j = 0; j < 6; j++) xv[nt][j] = xp[j];
    }
  }
  __syncthreads();
  float bt4[4][4], bg4[4][4];
#pragma unroll
  for (int mt = 0; mt < 4; mt++)
#pragma unroll
    for (int r = 0; r < 4; r++) {
      bt4[mt][r] = Bts[mt * 16 + q * 4 + r];
      bg4[mt][r] = Bgs[mt * 16 + q * 4 + r];
    }

  u16* myt2 = t2buf[w];
  const long orowbase = (long)((b * 22 + t) * 16) << 11;

#pragma unroll
  for (int nt = 0; nt < 4; nt++) {
    s16x8 pfrag = (s16x8){0, 0, 0, 0, 0, 0, 0, 0};
    if (q == 0) {
#pragma unroll
      for (int j = 0; j < 6; j++) pfrag[j] = (short)f2bf(xv[nt][j]);
    }
    f32x4 acc1[8];
#pragma unroll
    for (int mt = 0; mt < 8; mt++) acc1[mt] = f32x4{0.f, 0.f, 0.f, 0.f};
#pragma unroll
    for (int mt = 0; mt < 8; mt++)
      acc1[mt] = __builtin_amdgcn_mfma_f32_16x16x32_bf16(wfrag[mt], pfrag, acc1[mt], 0, 0, 0);

#pragma unroll
    for (int mt = 0; mt < 4; mt++) {
      u32 pk[2];
      u16 pv[4];
#pragma unroll
      for (int r = 0; r < 4; r++) {
        const float temp = acc1[mt][r] + bt4[mt][r];
        const float ga = acc1[mt + 4][r] + bg4[mt][r];
        pv[r] = f2bf(fmaxf(temp * sigmoidf(ga), 0.0f));
      }
      pk[0] = (u32)pv[0] | ((u32)pv[1] << 16);
      pk[1] = (u32)pv[2] | ((u32)pv[3] << 16);
      const int g = (mt * 4 + q) >> 1, half = q & 1;
      *(uint2*)(myt2 + lm * 64 + (g ^ (lm & 7)) * 8 + half * 4) = make_uint2(pk[0], pk[1]);
    }

    f32x4 acc2 = f32x4{0.f, 0.f, 0.f, 0.f};
#pragma unroll
    for (int kk = 0; kk < 2; kk++) {
      s16x8 af = *(const s16x8*)(myt2 + lm * 64 + ((kk * 4 + q) ^ (lm & 7)) * 8);
      acc2 = __builtin_amdgcn_mfma_f32_16x16x32_bf16(af, tfrag[kk], acc2, 0, 0, 0);
    }
    u16 ov[4];
#pragma unroll
    for (int r = 0; r < 4; r++) ov[r] = f2bf(acc2[r]);
    *(uint2*)(U1 + orowbase + ((long)lm << 11) + n0 + nt * 16 + q * 4) =
        make_uint2((u32)ov[0] | ((u32)ov[1] << 16), (u32)ov[2] | ((u32)ov[3] << 16));
  }
}

// ---------------------------------------------------------------------------
// Spatial GEMM (NT): C[i,col] = sum_j A[i,j] * X[col, j]  (+ optional relu)
// R1 structure + bijective XCD swizzle (verified R9). Do not re-pipeline
// (R2 regression).
// ---------------------------------------------------------------------------
template <int RELU>
__global__ __launch_bounds__(256, 3) void sp_gemm(
    const u16* __restrict__ A, const u16* __restrict__ X,
    u16* __restrict__ C, int Ncols, int nwg)
{
  __shared__ u16 ldsA[128 * 64];
  __shared__ u16 ldsB[128 * 64];
  const int lane = threadIdx.x & 63;
  const int w = threadIdx.x >> 6;

  const int h = blockIdx.x;
  const int bx = (h & 7) * (nwg >> 3) + (h >> 3);   // bijective for nwg%8==0

  const int ct = bx >> 4;
  const int rt = bx & 15;
  const int i0 = rt * 128;
  const int c0 = ct * 128;

  const int wm = w & 1, wn = w >> 1;
  const int lm = lane & 15, q = lane >> 4;

  f32x4 acc[4][4];
#pragma unroll
  for (int a = 0; a < 4; a++)
#pragma unroll
    for (int b2 = 0; b2 < 4; b2++) acc[a][b2] = f32x4{0.f, 0.f, 0.f, 0.f};

  const int srow = lane >> 3;
  const int sg = (lane & 7) ^ srow;
  const u16* gA = A + ((long)(i0 + w * 32 + srow) << 11) + sg * 8;
  const u16* gB = X + ((long)(c0 + w * 32 + srow) << 11) + sg * 8;
  u16* lA = ldsA + w * 2048;
  u16* lB = ldsB + w * 2048;

  for (int k0 = 0; k0 < 2048; k0 += 64) {
    __syncthreads();
#pragma unroll
    for (int j = 0; j < 4; j++) {
      async16(gA + j * 16384 + k0, lA + j * 512);
      async16(gB + j * 16384 + k0, lB + j * 512);
    }
    __syncthreads();
#pragma unroll
    for (int kk = 0; kk < 2; kk++) {
      const int ph = (kk * 4 + q) ^ (lm & 7);
      s16x8 af[4], bfr[4];
#pragma unroll
      for (int mt = 0; mt < 4; mt++)
        af[mt] = *(const s16x8*)(ldsA + (wm * 64 + mt * 16 + lm) * 64 + ph * 8);
#pragma unroll
      for (int nt = 0; nt < 4; nt++)
        bfr[nt] = *(const s16x8*)(ldsB + (wn * 64 + nt * 16 + lm) * 64 + ph * 8);
#pragma unroll
      for (int mt = 0; mt < 4; mt++)
#pragma unroll
        for (int nt = 0; nt < 4; nt++)
          acc[mt][nt] = __builtin_amdgcn_mfma_f32_16x16x32_bf16(af[mt], bfr[nt], acc[mt][nt], 0, 0, 0);
    }
  }

#pragma unroll
  for (int mt = 0; mt < 4; mt++) {
#pragma unroll
    for (int r = 0; r < 4; r++) {
      const long i = i0 + wm * 64 + mt * 16 + q * 4 + r;
      u16* crow = C + i * Ncols + c0 + wn * 64 + lm;
#pragma unroll
      for (int nt = 0; nt < 4; nt++) {
        float v = acc[mt][nt][r];
        if (RELU) v = fmaxf(v, 0.0f);
        crow[nt * 16] = f2bf(v);
      }
    }
  }
}

// ---------------------------------------------------------------------------
// Fused timeblock pair v8 = R9-verified kernel (310us, grid 512/512 — R10's
// MODE1 t-split reverted: correctness-clean but end-to-end regressed
// 310->323) + ONE change: bias folded into the gate-MFMA accumulator init
// (C-operand = bias vector; lane's 4 acc slots are channels cw..cw+3).
// Removes 64 VALU adds/iter/lane from the two gate epilogues. Safe by
// construction: only reorders finite f32 adds (<=1-2 ulp bf16), cannot NaN.
// This also closes the R8 post-mortem: pk-theta is the convicted poison
// (R10 isolated the t-split without it and passed).
// PARKED (do not re-roll): pk_bf16 theta GLOBAL store (convicted);
// R4-style 2-phase pipelining (un-diagnosed).
// ---------------------------------------------------------------------------
template <int TIN, int MODE>
__global__ __launch_bounds__(256, 2) void tbf_fused(
    const u16* __restrict__ in, const u16* __restrict__ W1c,
    const float* __restrict__ b1, const u16* __restrict__ W2c,
    const float* __restrict__ b2, const float* __restrict__ th,
    const u16* __restrict__ fwT, const float* __restrict__ fb,
    u16* __restrict__ outU, float* __restrict__ outF)
{
  constexpr int T1OUT = TIN - 2;            // TB-first outputs (iters)
  constexpr int T2OUT = TIN - 4;            // TB-second outputs
  constexpr int NC = TIN * 256;             // input row stride (u16)

  __shared__ __align__(16) u16 ring[8 * 1024];       // 16384 B
  __shared__ __align__(16) u16 h2r[3 * 64 * 64];     // 24576 B
  __shared__ __align__(16) u16 h3b[64 * 64];         //  8192 B
  __shared__ __align__(16) u16 sfw[(MODE == 0) ? 12 * 904 : 8];  // 21696 B (MODE0)

  const int tid = threadIdx.x;
  const int lane = tid & 63;
  const int w = tid >> 6;
  const int lm = lane & 15, q = lane >> 4;
  const int bx = blockIdx.x;
  const int n0 = (bx & 31) << 6;
  const int b = bx >> 5;

  // ---- weights -> regs (A-operand: row lm = out-channel w*16+lm) ---------
  s16x8 wfA[2][2];
  {
    const u16* wp = W1c + (w * 16 + lm) * 64 + q * 8;
#pragma unroll
    for (int kk = 0; kk < 2; kk++) {
      wfA[0][kk] = *(const s16x8*)(wp + kk * 32);
      wfA[1][kk] = *(const s16x8*)(wp + 64 * 64 + kk * 32);
    }
  }
  s16x8 wfB[2][6];
  {
    const u16* wp = W2c + (w * 16 + lm) * 192 + q * 8;
#pragma unroll
    for (int kk = 0; kk < 6; kk++) {
      wfB[0][kk] = *(const s16x8*)(wp + kk * 32);
      wfB[1][kk] = *(const s16x8*)(wp + 64 * 192 + kk * 32);
    }
  }
  // per-lane channel block for swapped-D epilogues: ch = cw + r
  const int cw = w * 16 + q * 4;
  float bsA4[4], bgA4[4], bsB4[4], bgB4[4];
#pragma unroll
  for (int r = 0; r < 4; r++) {
    bsA4[r] = b1[cw + r] + b1[64 + cw + r];
    bgA4[r] = b1[128 + cw + r];
    bsB4[r] = b2[cw + r] + b2[64 + cw + r];
    bgB4[r] = b2[128 + cw + r];
  }

  s16x8 tfrag[2];
  const int srow12 = (lm < 12) ? lm : (lm - 12);
  if constexpr (MODE == 1) {
#pragma unroll
    for (int kk = 0; kk < 2; kk++)
#pragma unroll
      for (int j = 0; j < 8; j++)
        tfrag[kk][j] = (short)f2bf(th[(kk * 32 + q * 8 + j) * 16 + lm]);
  } else {
    // FC weights: 12 real p-rows, stride 904 (16B mult, bank-spread).
#pragma unroll
    for (int i = 0; i < 6; i++) {
      const int g = i * 256 + tid;              // granules of 8 u16
      if (g < 12 * 112) {
        const int p = g / 112, k8 = g - p * 112;
        *(s16x8*)(sfw + p * 904 + k8 * 8) = *(const s16x8*)(fwT + g * 8);
      }
    }
  }
  // materialize prologue VGPR loads, then drain VM queue so the counted
  // vmcnt ladder below sees only segment loads (+ MODE1 theta stores).
  asm volatile("" : "+v"(bsA4[0]), "+v"(bsA4[1]), "+v"(bsA4[2]), "+v"(bsA4[3]),
                    "+v"(bgA4[0]), "+v"(bgA4[1]), "+v"(bgA4[2]), "+v"(bgA4[3]),
                    "+v"(bsB4[0]), "+v"(bsB4[1]), "+v"(bsB4[2]), "+v"(bsB4[3]),
                    "+v"(bgB4[0]), "+v"(bgB4[1]), "+v"(bgB4[2]), "+v"(bgB4[3]));
  asm volatile("s_waitcnt vmcnt(0)" ::: "memory");

  // ---- segment staging: pairs of 2 t-steps, all 256 threads, 1 load each --
  const int k7 = tid & 127;                   // position within a seg (x16B)
  const int segsel = tid >> 7;                // 0/1: which seg of the pair
  const u16* rowp = in + (long)(n0 + (k7 >> 1)) * NC + (long)(b * TIN) * 16 + (k7 & 1) * 8;

  auto issue_pair = [&](int tp) {
    const int seg = tp + segsel;
    async16(rowp + seg * 16, ring + ((seg & 7) << 10) + k7 * 8);
  };

  issue_pair(0); issue_pair(2); issue_pair(4);   // segs 0..5 in flight

  u16* h2w = h2r;                 // h(t)   write slot
  u16* h2m = h2r + 64 * 64;       // h(t-1)
  u16* h2o = h2r + 2 * 64 * 64;   // h(t-2)
  f32x4 accfc = f32x4{0.f, 0.f, 0.f, 0.f};

  const int gw8 = 2 * w + (q >> 1);   // granule of cw within a 64-u16 h row
  const int wofs = (q & 1) << 2;      // u16 offset within granule

#pragma unroll 1
  for (int t = 0; t < T1OUT; ++t) {
    // gate: required pair retired. MODE1 queue per iter = {L, S}; MODE0 = {L}.
    if constexpr (MODE == 1) {
      if (t < 3) asm volatile("s_waitcnt vmcnt(1) lgkmcnt(0)" ::: "memory");
      else       asm volatile("s_waitcnt vmcnt(2) lgkmcnt(0)" ::: "memory");
    } else {
      if (t < 13) asm volatile("s_waitcnt vmcnt(1) lgkmcnt(0)" ::: "memory");
      else        asm volatile("s_waitcnt vmcnt(0) lgkmcnt(0)" ::: "memory");
    }
    __builtin_amdgcn_s_barrier();

    if (((t & 1) == 0) && t <= TIN - 8) issue_pair(t + 6);

    // ---- TB-first: K=64 window over ring segs t..t+3 (swapped operands) --
    {
      f32x4 aA[4][2];
#pragma unroll
      for (int m = 0; m < 4; m++) {
        aA[m][0] = f32x4{bsA4[0], bsA4[1], bsA4[2], bsA4[3]};  // bias as C-in
        aA[m][1] = f32x4{bgA4[0], bgA4[1], bgA4[2], bgA4[3]};
      }
#pragma unroll
      for (int kk = 0; kk < 2; kk++) {
        const int slotb = ((t + 2 * kk + (q >> 1)) & 7) << 10;
        const int off = slotb + (q & 1) * 8;
#pragma unroll
        for (int nt = 0; nt < 4; nt++) {
          s16x8 pf = *(const s16x8*)(ring + off + (nt * 16 + lm) * 16);
          aA[nt][0] = __builtin_amdgcn_mfma_f32_16x16x32_bf16(wfA[0][kk], pf, aA[nt][0], 0, 0, 0);
          aA[nt][1] = __builtin_amdgcn_mfma_f32_16x16x32_bf16(wfA[1][kk], pf, aA[nt][1], 0, 0, 0);
        }
      }
      // gate epilogue -> h2w (swizzled b64: node nt*16+lm, ch cw..cw+3)
#pragma unroll
      for (int nt = 0; nt < 4; nt++) {
        float hv[4];
#pragma unroll
        for (int r = 0; r < 4; r++)
          hv[r] = fmaxf(aA[nt][0][r] * sigmoidf(aA[nt][1][r]), 0.0f);
        *(uint2*)(h2w + ((nt * 16 + lm) << 6) + ((gw8 ^ (lm & 7)) << 3) + wofs) =
            make_uint2(pk_bf16(hv[0], hv[1]), pk_bf16(hv[2], hv[3]));
      }
    }
    asm volatile("s_waitcnt lgkmcnt(0)" ::: "memory");
    __builtin_amdgcn_s_barrier();

    if (t >= 2) {
      // ---- TB-second: K=192 over h(t-2), h(t-1), h(t) (swizzled reads) ---
      f32x4 aB[4][2];
#pragma unroll
      for (int m = 0; m < 4; m++) {
        aB[m][0] = f32x4{bsB4[0], bsB4[1], bsB4[2], bsB4[3]};  // bias as C-in
        aB[m][1] = f32x4{bgB4[0], bgB4[1], bgB4[2], bgB4[3]};
      }
#pragma unroll
      for (int kk3 = 0; kk3 < 6; kk3++) {
        const u16* hp = (kk3 < 2) ? h2o : ((kk3 < 4) ? h2m : h2w);
        const int gr = (kk3 & 1) * 4 + q;
#pragma unroll
        for (int nt = 0; nt < 4; nt++) {
          s16x8 pf = *(const s16x8*)(hp + ((nt * 16 + lm) << 6) + ((gr ^ (lm & 7)) << 3));
          aB[nt][0] = __builtin_amdgcn_mfma_f32_16x16x32_bf16(wfB[0][kk3], pf, aB[nt][0], 0, 0, 0);
          aB[nt][1] = __builtin_amdgcn_mfma_f32_16x16x32_bf16(wfB[1][kk3], pf, aB[nt][1], 0, 0, 0);
        }
      }
      // gate epilogue -> h3b (swizzled b64)
#pragma unroll
      for (int nt = 0; nt < 4; nt++) {
        float hv[4];
#pragma unroll
        for (int r = 0; r < 4; r++)
          hv[r] = fmaxf(aB[nt][0][r] * sigmoidf(aB[nt][1][r]), 0.0f);
        *(uint2*)(h3b + ((nt * 16 + lm) << 6) + ((gw8 ^ (lm & 7)) << 3) + wofs) =
            make_uint2(pk_bf16(hv[0], hv[1]), pk_bf16(hv[2], hv[3]));
      }
      asm volatile("s_waitcnt lgkmcnt(0)" ::: "memory");
      __builtin_amdgcn_s_barrier();

      const int t2 = t - 2;
      if constexpr (MODE == 1) {
        f32x4 a4 = f32x4{0.f, 0.f, 0.f, 0.f};
#pragma unroll
        for (int kk = 0; kk < 2; kk++) {
          s16x8 af = *(const s16x8*)(h3b + ((w * 16 + lm) << 6) + (((kk * 4 + q) ^ (lm & 7)) << 3));
          a4 = __builtin_amdgcn_mfma_f32_16x16x32_bf16(af, tfrag[kk], a4, 0, 0, 0);
        }
        u16 ov[4];
#pragma unroll
        for (int r = 0; r < 4; r++) ov[r] = f2bf(a4[r]);
        const long orowbase = (long)((b * T2OUT + t2) * 16) << 11;
        *(uint2*)(outU + orowbase + ((long)lm << 11) + n0 + w * 16 + q * 4) =
            make_uint2((u32)ov[0] | ((u32)ov[1] << 16), (u32)ov[2] | ((u32)ov[3] << 16));
      } else {
#pragma unroll
        for (int kk = 0; kk < 2; kk++) {
          s16x8 af = *(const s16x8*)(h3b + ((w * 16 + lm) << 6) + (((kk * 4 + q) ^ (lm & 7)) << 3));
          s16x8 bfr = *(const s16x8*)(sfw + srow12 * 904 + t2 * 64 + kk * 32 + q * 8);
          accfc = __builtin_amdgcn_mfma_f32_16x16x32_bf16(af, bfr, accfc, 0, 0, 0);
        }
      }
    }
    // rotate h slots: (t-2) slot becomes next write slot
    u16* tmp = h2o; h2o = h2m; h2m = h2w; h2w = tmp;
  }

  if constexpr (MODE == 0) {
    if (lm < 12) {
      const float bfc = fb[lm];
#pragma unroll
      for (int r = 0; r < 4; r++) {
        const int n = n0 + w * 16 + q * 4 + r;
        outF[((long)b * 2048 + n) * 12 + lm] = accfc[r] + bfc;
      }
    }
  }
}

// ---------------------------------------------------------------------------
extern "C" void kernel_launch(void* const* d_in, const int* in_sizes, int n_in,
                              void* d_out, int out_size, void* d_ws, size_t ws_size,
                              hipStream_t stream)
{
  const float* x    = (const float*)d_in[0];
  const float* A    = (const float*)d_in[1];
  const float* tb1w = (const float*)d_in[2];
  const float* tb1b = (const float*)d_in[3];
  const float* th1  = (const float*)d_in[4];
  const float* tb2w = (const float*)d_in[5];
  const float* tb2b = (const float*)d_in[6];
  const float* tb3w = (const float*)d_in[7];
  const float* tb3b = (const float*)d_in[8];
  const float* th2  = (const float*)d_in[9];
  const float* tb4w = (const float*)d_in[10];
  const float* tb4b = (const float*)d_in[11];
  const float* tb5w = (const float*)d_in[12];
  const float* tb5b = (const float*)d_in[13];
  const float* fw   = (const float*)d_in[14];
  const float* fb   = (const float*)d_in[15];
  float* out = (float*)d_out;

  char* ws = (char*)d_ws;
  u16* Abf  = (u16*)(ws + 0);            //  8,388,608 B
  u16* W2   = (u16*)(ws + 8388608);      //     16,384
  u16* W3   = (u16*)(ws + 8404992);      //     49,152
  u16* W4   = (u16*)(ws + 8454144);      //     16,384
  u16* W5   = (u16*)(ws + 8470528);      //     49,152
  u16* bufA = (u16*)(ws + 8519680);      // 92,274,688
  u16* bufB = (u16*)(ws + 100794368);    // 92,274,688
  u16* W1   = (u16*)(ws + 8519680 + 88000000);  // 2 KB, in bufA tail slack
  u16* FWT  = (u16*)(ws + 8519680 + 88004096);  // 28,672 B, bufA tail slack

  prep_all<<<4412, 256, 0, stream>>>(A, Abf, out + 393216,
                                     tb1w, W1, tb2w, W2, tb3w, W3,
                                     tb4w, W4, tb5w, W5, fw, FWT);

  // ---- block 1:  U1 = TB1(x)*th1; t2 = relu(A*U1); U2 = TB3(TB2(t2))*th2
  tb1_kernel<<<dim3(8, 16, 22), 256, 0, stream>>>(x, W1, tb1b, th1, bufA);
  sp_gemm<1><<<44 * 16, 256, 0, stream>>>(Abf, bufA, bufB, 5632, 44 * 16);
  tbf_fused<22, 1><<<512, 256, 0, stream>>>(bufB, W2, tb2b, W3, tb3b, th2,
                                            nullptr, nullptr, bufA, nullptr);
  // ---- block 2:  t2 = relu(A*U2); out = FC(TB5(TB4(t2)))
  sp_gemm<1><<<36 * 16, 256, 0, stream>>>(Abf, bufA, bufB, 4608, 36 * 16);
  tbf_fused<18, 0><<<512, 256, 0, stream>>>(bufB, W4, tb4b, W5, tb5b, nullptr,
                                            FWT, fb, nullptr, out);
}